// Round 1
// baseline (123.578 us; speedup 1.0000x reference)
//
#include <hip/hip_runtime.h>

// Problem constants (from reference setup_inputs): D=128, stride=2 -> Dp=64
#define DP   64
#define CH   64
#define NSEG (DP * DP * DP)   // 262144 cells

// ---- monotone float<->uint key mapping -------------------------------------
// key order == float order; key 0 is below every encodable finite float,
// so it doubles as the "empty cell" sentinel.
__device__ __forceinline__ unsigned int f2key(float f) {
    unsigned int b = __float_as_uint(f);
    return (b & 0x80000000u) ? ~b : (b | 0x80000000u);
}
__device__ __forceinline__ float key2f(unsigned int k) {
    if (k == 0u) return 0.0f;  // empty segment -> 0 (matches reference)
    unsigned int b = (k & 0x80000000u) ? (k ^ 0x80000000u) : ~k;
    return __uint_as_float(b);
}

// ---- kernel 1: zero the pooled-key buffer (re-run every call) --------------
__global__ void pool_init_kernel(uint4* __restrict__ pooled4, int n4) {
    int i = blockIdx.x * blockDim.x + threadIdx.x;
    int stride = gridDim.x * blockDim.x;
    uint4 z; z.x = 0u; z.y = 0u; z.z = 0u; z.w = 0u;
    for (; i < n4; i += stride) pooled4[i] = z;
}

// ---- kernel 2: scatter segment-max via atomicMax on monotone keys ----------
// One thread per (point, channel). Lanes of a wave share one point.
__global__ void pool_scatter_kernel(const float* __restrict__ feats,
                                    const int*   __restrict__ coords,
                                    unsigned int* __restrict__ pooled,
                                    int total) {
    int i = blockIdx.x * blockDim.x + threadIdx.x;
    if (i >= total) return;
    int pt = i >> 6;      // point index
    int ch = i & 63;      // channel
    int x = coords[pt * 3 + 0] >> 1;
    int y = coords[pt * 3 + 1] >> 1;
    int z = coords[pt * 3 + 2] >> 1;
    int seg = (x * DP + y) * DP + z;
    unsigned int key = f2key(feats[i]);
    atomicMax(&pooled[seg * CH + ch], key);
}

// ---- kernel 3: gather parent cell's pooled row onto b sites ----------------
// One thread per 4 channels: uint4 in, float4 out.
__global__ void pool_gather_kernel(const int*   __restrict__ bcoords,
                                   const uint4* __restrict__ pooled4,
                                   float4*      __restrict__ out,
                                   int total4) {
    int i = blockIdx.x * blockDim.x + threadIdx.x;
    if (i >= total4) return;
    int pt = i >> 4;      // 16 uint4 chunks per point (64 ch / 4)
    int q  = i & 15;
    int x = bcoords[pt * 3 + 0] >> 1;
    int y = bcoords[pt * 3 + 1] >> 1;
    int z = bcoords[pt * 3 + 2] >> 1;
    int seg = (x * DP + y) * DP + z;
    uint4 k = pooled4[seg * (CH / 4) + q];
    float4 o;
    o.x = key2f(k.x);
    o.y = key2f(k.y);
    o.z = key2f(k.z);
    o.w = key2f(k.w);
    out[i] = o;
}

extern "C" void kernel_launch(void* const* d_in, const int* in_sizes, int n_in,
                              void* d_out, int out_size, void* d_ws, size_t ws_size,
                              hipStream_t stream) {
    const float* a_feats  = (const float*)d_in[0];
    const int*   a_coords = (const int*)d_in[1];
    const int*   b_coords = (const int*)d_in[2];
    // d_in[3] = spatial_size (=128 per reference); pooled grid hardcoded DP=64.

    int NA = in_sizes[0] / CH;
    int NB = in_sizes[2] / 3;

    unsigned int* pooled = (unsigned int*)d_ws;  // NSEG*CH*4 = 64 MiB

    // 1) init keys to 0 (empty sentinel) — must run every call (no re-poison)
    int n4 = NSEG * CH / 4;
    pool_init_kernel<<<2048, 256, 0, stream>>>((uint4*)pooled, n4);

    // 2) scatter-max
    int total = NA * CH;
    pool_scatter_kernel<<<(total + 255) / 256, 256, 0, stream>>>(
        a_feats, a_coords, pooled, total);

    // 3) gather
    int total4 = NB * CH / 4;
    pool_gather_kernel<<<(total4 + 255) / 256, 256, 0, stream>>>(
        b_coords, (const uint4*)pooled, (float4*)d_out, total4);
}